// Round 1
// baseline (273.508 us; speedup 1.0000x reference)
//
#include <hip/hip_runtime.h>

// HybridLoss: 0.8*MSE + 0.2*(1-SSIM), SSIM via separable 11x11 Gaussian (sigma=1.5)
// Input: pred, target f32 (32,3,512,512). Output: scalar f32.

#define W 512
#define H 512
#define NIMG 96            // 32*3 independent channels
#define TX 64
#define TY 32
#define HALO 5
#define SXW (TX + 2*HALO)  // 74
#define SYH (TY + 2*HALO)  // 42
#define NSLOT 64

__global__ void hybrid_init(double* __restrict__ ws) {
    int t = blockIdx.x * blockDim.x + threadIdx.x;
    if (t < 2 * NSLOT) ws[t] = 0.0;
}

__global__ __launch_bounds__(256) void hybrid_main(
    const float* __restrict__ pred, const float* __restrict__ targ,
    double* __restrict__ ws)
{
    __shared__ float  s_x[SYH][SXW];    // clipped pred tile (+halo)
    __shared__ float  s_y[SYH][SXW];    // target tile (+halo)
    __shared__ float4 s_h4[SYH][TX];    // hconv: (mu_x, mu_y, xx, yy)
    __shared__ float  s_hxy[SYH][TX];   // hconv: xy
    __shared__ float  redm[4], reds[4];

    const int tid = threadIdx.x;
    const int img = blockIdx.z;
    const float* __restrict__ pp = pred + (size_t)img * (H * W);
    const float* __restrict__ tp = targ + (size_t)img * (H * W);
    const int x0 = blockIdx.x * TX - HALO;
    const int y0 = blockIdx.y * TY - HALO;

    // Normalized 1D Gaussian weights (separable form of outer(g,g)/sum)
    float gw[11];
    {
        float s = 0.f;
#pragma unroll
        for (int k = 0; k < 11; ++k) {
            float d = (float)(k - 5);
            gw[k] = expf(-d * d / 4.5f);   // 2*sigma^2 = 4.5
            s += gw[k];
        }
        float inv = 1.f / s;
#pragma unroll
        for (int k = 0; k < 11; ++k) gw[k] *= inv;
    }

    // ---- Stage tile + halo into LDS; accumulate MSE over interior ----
    float mse_local = 0.f;
    for (int i = tid; i < SYH * SXW; i += 256) {
        int r = i / SXW, c = i - r * SXW;
        int gx = x0 + c, gy = y0 + r;
        float pv = 0.f, tv = 0.f;
        if (gx >= 0 && gx < W && gy >= 0 && gy < H) {
            pv = pp[gy * W + gx];
            tv = tp[gy * W + gx];
        }
        s_x[r][c] = fminf(fmaxf(pv, 0.f), 1.f);  // SSIM uses clipped pred
        s_y[r][c] = tv;
        // MSE uses raw pred; interior of tile = exact partition of image
        if (c >= HALO && c < HALO + TX && r >= HALO && r < HALO + TY) {
            float d = pv - tv;
            mse_local += d * d;
        }
    }
    __syncthreads();

    // ---- Horizontal 11-tap conv of {x, y, x^2, y^2, xy} ----
    // Each wave handles one row (c = lane) -> conflict-free LDS.
    for (int i = tid; i < SYH * TX; i += 256) {
        int r = i >> 6, c = i & 63;
        float mx = 0.f, my = 0.f, xx = 0.f, yy = 0.f, xy = 0.f;
#pragma unroll
        for (int k = 0; k < 11; ++k) {
            float w  = gw[k];
            float xv = s_x[r][c + k];
            float yv = s_y[r][c + k];
            float wx = w * xv, wy = w * yv;
            mx += wx; my += wy;
            xx = fmaf(wx, xv, xx);
            yy = fmaf(wy, yv, yy);
            xy = fmaf(wx, yv, xy);
        }
        s_h4[r][c]  = make_float4(mx, my, xx, yy);
        s_hxy[r][c] = xy;
    }
    __syncthreads();

    // ---- Vertical 11-tap conv + SSIM map + accumulate ----
    float ssim_local = 0.f;
    const float C1 = 1e-4f;   // (0.01*1)^2
    const float C2 = 9e-4f;   // (0.03*1)^2
    for (int i = tid; i < TY * TX; i += 256) {
        int r = i >> 6, c = i & 63;
        float mx = 0.f, my = 0.f, xx = 0.f, yy = 0.f, xy = 0.f;
#pragma unroll
        for (int j = 0; j < 11; ++j) {
            float w = gw[j];
            float4 h = s_h4[r + j][c];
            mx = fmaf(w, h.x, mx);
            my = fmaf(w, h.y, my);
            xx = fmaf(w, h.z, xx);
            yy = fmaf(w, h.w, yy);
            xy = fmaf(w, s_hxy[r + j][c], xy);
        }
        float mu_x2 = mx * mx, mu_y2 = my * my, mu_xy = mx * my;
        float sx2 = xx - mu_x2, sy2 = yy - mu_y2, sxy = xy - mu_xy;
        float num = (2.f * mu_xy + C1) * (2.f * sxy + C2);
        float den = (mu_x2 + mu_y2 + C1) * (sx2 + sy2 + C2);
        ssim_local += num / den;
    }

    // ---- Block reduction: wave shuffle then cross-wave via LDS ----
    float m = mse_local, s2 = ssim_local;
#pragma unroll
    for (int off = 32; off; off >>= 1) {
        m  += __shfl_down(m, off);
        s2 += __shfl_down(s2, off);
    }
    int wid = tid >> 6;
    if ((tid & 63) == 0) { redm[wid] = m; reds[wid] = s2; }
    __syncthreads();
    if (tid == 0) {
        double mt = (double)redm[0] + (double)redm[1] + (double)redm[2] + (double)redm[3];
        double st = (double)reds[0] + (double)reds[1] + (double)reds[2] + (double)reds[3];
        int slot = (blockIdx.x + blockIdx.y * 8 + blockIdx.z * 128) & (NSLOT - 1);
        atomicAdd(&ws[slot], mt);
        atomicAdd(&ws[NSLOT + slot], st);
    }
}

__global__ void hybrid_fin(const double* __restrict__ ws, float* __restrict__ out) {
    int t = threadIdx.x;  // 64 threads
    double m = ws[t];
    double s = ws[NSLOT + t];
#pragma unroll
    for (int off = 32; off; off >>= 1) {
        m += __shfl_down(m, off);
        s += __shfl_down(s, off);
    }
    if (t == 0) {
        const double N = (double)NIMG * H * W;
        double mse  = m / N;
        double ssim = s / N;
        out[0] = (float)(0.8 * mse + 0.2 * (1.0 - ssim));
    }
}

extern "C" void kernel_launch(void* const* d_in, const int* in_sizes, int n_in,
                              void* d_out, int out_size, void* d_ws, size_t ws_size,
                              hipStream_t stream) {
    const float* pred = (const float*)d_in[0];
    const float* targ = (const float*)d_in[1];
    double* ws = (double*)d_ws;
    float* out = (float*)d_out;

    hybrid_init<<<1, 128, 0, stream>>>(ws);
    dim3 grid(W / TX, H / TY, NIMG);
    hybrid_main<<<grid, dim3(256), 0, stream>>>(pred, targ, ws);
    hybrid_fin<<<1, 64, 0, stream>>>(ws, out);
}

// Round 2
// 244.125 us; speedup vs baseline: 1.1204x; 1.1204x over previous
//
#include <hip/hip_runtime.h>

// HybridLoss: 0.8*MSE + 0.2*(1-SSIM), SSIM via separable 11x11 Gaussian (sigma=1.5)
// Input: pred, target f32 (32,3,512,512). Output: scalar f32.
// Structure: fused hconv-from-global (register runs) -> LDS -> vconv+SSIM.

#define W 512
#define H 512
#define NIMG 96            // 32*3 independent channels
#define TX 64
#define TY 32
#define HALO 5
#define ROWS (TY + 2*HALO) // 42
#define NGRP 16            // 4-column groups per row
#define NTASK (ROWS * NGRP)
#define NSLOT 64

__global__ void hybrid_init(double* __restrict__ ws) {
    int t = blockIdx.x * blockDim.x + threadIdx.x;
    if (t < 2 * NSLOT) ws[t] = 0.0;
}

__global__ __launch_bounds__(256) void hybrid_main(
    const float* __restrict__ pred, const float* __restrict__ targ,
    double* __restrict__ ws)
{
    __shared__ float4 s_h4[ROWS][TX];   // hconv: (mu_x, mu_y, xx, yy)  43008 B
    __shared__ float  s_hxy[ROWS][TX];  // hconv: xy                    10752 B
    __shared__ float  redm[4], reds[4];

    const int tid = threadIdx.x;
    const int img = blockIdx.z;
    const float* __restrict__ pp = pred + (size_t)img * (H * W);
    const float* __restrict__ tp = targ + (size_t)img * (H * W);
    const int xbase = blockIdx.x * TX;
    const int y0 = blockIdx.y * TY - HALO;

    // Normalized 1D Gaussian weights (separable form of outer(g,g)/sum), f32 like ref
    float gw[11];
    {
        float s = 0.f;
#pragma unroll
        for (int k = 0; k < 11; ++k) {
            float d = (float)(k - 5);
            gw[k] = expf(-d * d / 4.5f);   // 2*sigma^2 = 4.5
            s += gw[k];
        }
        float inv = 1.f / s;
#pragma unroll
        for (int k = 0; k < 11; ++k) gw[k] *= inv;
    }

    // ---- Phase 1: load register runs, MSE, clip, horizontal 11-tap -> LDS ----
    float mse_local = 0.f;
    for (int i = tid; i < NTASK; i += 256) {
        const int r  = i >> 4;          // LDS row 0..41
        const int g  = i & 15;          // 4-col group
        const int c0 = g * 4;
        const int gy = y0 + r;

        if (gy < 0 || gy >= H) {        // zero-padded row: hconv of zeros = 0
            float4 z = make_float4(0.f, 0.f, 0.f, 0.f);
#pragma unroll
            for (int c = 0; c < 4; ++c) { s_h4[r][c0 + c] = z; s_hxy[r][c0 + c] = 0.f; }
            continue;
        }

        const int A0 = xbase + c0 - 8;  // aligned 20-px window [A0, A0+20)
        const float* __restrict__ px = pp + (size_t)gy * W;
        const float* __restrict__ py = tp + (size_t)gy * W;

        float xa[20], ya[20];
        if (A0 >= 0 && A0 + 20 <= W) {  // fast path: 5 aligned float4 loads each
            const float4* qx = (const float4*)(px + A0);
            const float4* qy = (const float4*)(py + A0);
#pragma unroll
            for (int v = 0; v < 5; ++v) {
                float4 a = qx[v], b = qy[v];
                xa[4*v+0] = a.x; xa[4*v+1] = a.y; xa[4*v+2] = a.z; xa[4*v+3] = a.w;
                ya[4*v+0] = b.x; ya[4*v+1] = b.y; ya[4*v+2] = b.z; ya[4*v+3] = b.w;
            }
        } else {                        // image-edge groups only
#pragma unroll
            for (int j = 0; j < 20; ++j) {
                int col = A0 + j;
                bool ok = (col >= 0) && (col < W);
                xa[j] = ok ? px[col] : 0.f;
                ya[j] = ok ? py[col] : 0.f;
            }
        }

        // MSE on raw pred over owned (interior-row) pixels: exact partition
        if (r >= HALO && r < HALO + TY) {
#pragma unroll
            for (int c = 0; c < 4; ++c) {
                float d = xa[8 + c] - ya[8 + c];
                mse_local = fmaf(d, d, mse_local);
            }
        }
        // SSIM uses clipped pred (only positions 3..16 feed the conv)
#pragma unroll
        for (int j = 3; j < 17; ++j) xa[j] = fminf(fmaxf(xa[j], 0.f), 1.f);

        float a0[4] = {0,0,0,0}, a1[4] = {0,0,0,0}, a2[4] = {0,0,0,0};
        float a3[4] = {0,0,0,0}, a4[4] = {0,0,0,0};
#pragma unroll
        for (int k = 0; k < 11; ++k) {
            float w = gw[k];
#pragma unroll
            for (int c = 0; c < 4; ++c) {
                float xv = xa[3 + c + k], yv = ya[3 + c + k];
                float wx = w * xv, wy = w * yv;
                a0[c] += wx; a1[c] += wy;
                a2[c] = fmaf(wx, xv, a2[c]);
                a3[c] = fmaf(wy, yv, a3[c]);
                a4[c] = fmaf(wx, yv, a4[c]);
            }
        }
#pragma unroll
        for (int c = 0; c < 4; ++c) {
            s_h4[r][c0 + c]  = make_float4(a0[c], a1[c], a2[c], a3[c]);
            s_hxy[r][c0 + c] = a4[c];
        }
    }
    __syncthreads();

    // ---- Phase 2: vertical 11-tap (row pairs), SSIM map, accumulate ----
    float ssim_local = 0.f;
    const float C1 = 1e-4f;   // (0.01*1)^2
    const float C2 = 9e-4f;   // (0.03*1)^2
    for (int i = tid; i < (TY / 2) * TX; i += 256) {
        const int r2 = (i >> 6) * 2;   // output rows r2, r2+1
        const int c  = i & 63;
        float b0x=0,b0y=0,b0xx=0,b0yy=0,b0xy=0;
        float b1x=0,b1y=0,b1xx=0,b1yy=0,b1xy=0;
#pragma unroll
        for (int j = 0; j < 12; ++j) {
            float4 h  = s_h4[r2 + j][c];
            float hxy = s_hxy[r2 + j][c];
            if (j < 11) {
                float w = gw[j];
                b0x  = fmaf(w, h.x, b0x);  b0y  = fmaf(w, h.y, b0y);
                b0xx = fmaf(w, h.z, b0xx); b0yy = fmaf(w, h.w, b0yy);
                b0xy = fmaf(w, hxy, b0xy);
            }
            if (j >= 1) {
                float w = gw[j - 1];
                b1x  = fmaf(w, h.x, b1x);  b1y  = fmaf(w, h.y, b1y);
                b1xx = fmaf(w, h.z, b1xx); b1yy = fmaf(w, h.w, b1yy);
                b1xy = fmaf(w, hxy, b1xy);
            }
        }
        {
            float mu_x2 = b0x * b0x, mu_y2 = b0y * b0y, mu_xy = b0x * b0y;
            float sx2 = b0xx - mu_x2, sy2 = b0yy - mu_y2, sxy = b0xy - mu_xy;
            float num = (2.f * mu_xy + C1) * (2.f * sxy + C2);
            float den = (mu_x2 + mu_y2 + C1) * (sx2 + sy2 + C2);
            ssim_local += num / den;
        }
        {
            float mu_x2 = b1x * b1x, mu_y2 = b1y * b1y, mu_xy = b1x * b1y;
            float sx2 = b1xx - mu_x2, sy2 = b1yy - mu_y2, sxy = b1xy - mu_xy;
            float num = (2.f * mu_xy + C1) * (2.f * sxy + C2);
            float den = (mu_x2 + mu_y2 + C1) * (sx2 + sy2 + C2);
            ssim_local += num / den;
        }
    }

    // ---- Block reduction: wave shuffle then cross-wave via LDS ----
    float m = mse_local, s2 = ssim_local;
#pragma unroll
    for (int off = 32; off; off >>= 1) {
        m  += __shfl_down(m, off);
        s2 += __shfl_down(s2, off);
    }
    int wid = tid >> 6;
    if ((tid & 63) == 0) { redm[wid] = m; reds[wid] = s2; }
    __syncthreads();
    if (tid == 0) {
        double mt = (double)redm[0] + (double)redm[1] + (double)redm[2] + (double)redm[3];
        double st = (double)reds[0] + (double)reds[1] + (double)reds[2] + (double)reds[3];
        int slot = (blockIdx.x + blockIdx.y * 8 + blockIdx.z * 128) & (NSLOT - 1);
        atomicAdd(&ws[slot], mt);
        atomicAdd(&ws[NSLOT + slot], st);
    }
}

__global__ void hybrid_fin(const double* __restrict__ ws, float* __restrict__ out) {
    int t = threadIdx.x;  // 64 threads
    double m = ws[t];
    double s = ws[NSLOT + t];
#pragma unroll
    for (int off = 32; off; off >>= 1) {
        m += __shfl_down(m, off);
        s += __shfl_down(s, off);
    }
    if (t == 0) {
        const double N = (double)NIMG * H * W;
        double mse  = m / N;
        double ssim = s / N;
        out[0] = (float)(0.8 * mse + 0.2 * (1.0 - ssim));
    }
}

extern "C" void kernel_launch(void* const* d_in, const int* in_sizes, int n_in,
                              void* d_out, int out_size, void* d_ws, size_t ws_size,
                              hipStream_t stream) {
    const float* pred = (const float*)d_in[0];
    const float* targ = (const float*)d_in[1];
    double* ws = (double*)d_ws;
    float* out = (float*)d_out;

    hybrid_init<<<1, 128, 0, stream>>>(ws);
    dim3 grid(W / TX, H / TY, NIMG);
    hybrid_main<<<grid, dim3(256), 0, stream>>>(pred, targ, ws);
    hybrid_fin<<<1, 64, 0, stream>>>(ws, out);
}

// Round 3
// 212.742 us; speedup vs baseline: 1.2856x; 1.1475x over previous
//
#include <hip/hip_runtime.h>

// HybridLoss: 0.8*MSE + 0.2*(1-SSIM), SSIM via separable 11x11 Gaussian (sigma=1.5)
// Input: pred, target f32 (32,3,512,512). Output: scalar f32.
// fused hconv-from-global (register windows) -> padded LDS planes -> 4-row vconv runs.

#define W 512
#define H 512
#define NIMG 96            // 32*3 independent channels
#define TX 64
#define TY 16
#define HALO 5
#define ROWS (TY + 2*HALO) // 26
#define NTASK (ROWS * 16)  // 416 hconv tasks (4-col groups)
#define NSLOT 128

__global__ void hybrid_init(double* __restrict__ ws) {
    int t = blockIdx.x * blockDim.x + threadIdx.x;
    if (t < 2 * NSLOT) ws[t] = 0.0;
}

__global__ __launch_bounds__(256, 4) void hybrid_main(
    const float* __restrict__ pred, const float* __restrict__ targ,
    double* __restrict__ ws)
{
    // Padded planes: row strides 66/66/68 elems -> every wave access spreads
    // uniformly over all 32 banks (writes 8cyc, b64 reads 4cyc = conflict-free),
    // and rows stay 16-B aligned so float4 stores are legal.
    __shared__ float2 s_mxy[ROWS][66];  // (mu_x, mu_y)   13728 B
    __shared__ float2 s_sq [ROWS][66];  // (xx, yy)       13728 B
    __shared__ float  s_xy [ROWS][68];  // xy              7072 B

    const int tid = threadIdx.x;
    const int img = blockIdx.z;
    const float* __restrict__ pp = pred + (size_t)img * (H * W);
    const float* __restrict__ tp = targ + (size_t)img * (H * W);
    const int xbase = blockIdx.x * TX;
    const int y0 = blockIdx.y * TY - HALO;

    // Normalized 1D Gaussian (separable form of outer(g,g)/sum), f32 like ref
    float gw[11];
    {
        float s = 0.f;
#pragma unroll
        for (int k = 0; k < 11; ++k) {
            float d = (float)(k - 5);
            gw[k] = expf(-d * d / 4.5f);   // 2*sigma^2 = 4.5
            s += gw[k];
        }
        float inv = 1.f / s;
#pragma unroll
        for (int k = 0; k < 11; ++k) gw[k] *= inv;
    }

    // ---- Phase 1: register windows, MSE, clip, horizontal 11-tap -> LDS ----
    float mse_local = 0.f;
    for (int i = tid; i < NTASK; i += 256) {
        const int r  = i >> 4;          // LDS row 0..25
        const int g  = i & 15;          // 4-col group
        const int c0 = g * 4;
        const int gy = y0 + r;

        if (gy < 0 || gy >= H) {        // zero-padded row
            float4 z = make_float4(0.f, 0.f, 0.f, 0.f);
            *(float4*)&s_mxy[r][c0]     = z;
            *(float4*)&s_mxy[r][c0 + 2] = z;
            *(float4*)&s_sq [r][c0]     = z;
            *(float4*)&s_sq [r][c0 + 2] = z;
            *(float4*)&s_xy [r][c0]     = z;
            continue;
        }

        const int A0 = xbase + c0 - 8;  // aligned 20-px window [A0, A0+20)
        const float* __restrict__ px = pp + (size_t)gy * W;
        const float* __restrict__ py = tp + (size_t)gy * W;

        float xa[20], ya[20];
        if (A0 >= 0 && A0 + 20 <= W) {  // fast path: 5 aligned float4 loads each
            const float4* qx = (const float4*)(px + A0);
            const float4* qy = (const float4*)(py + A0);
#pragma unroll
            for (int v = 0; v < 5; ++v) {
                float4 a = qx[v], b = qy[v];
                xa[4*v+0] = a.x; xa[4*v+1] = a.y; xa[4*v+2] = a.z; xa[4*v+3] = a.w;
                ya[4*v+0] = b.x; ya[4*v+1] = b.y; ya[4*v+2] = b.z; ya[4*v+3] = b.w;
            }
        } else {                        // image-edge groups only
#pragma unroll
            for (int j = 0; j < 20; ++j) {
                int col = A0 + j;
                bool ok = (col >= 0) && (col < W);
                xa[j] = ok ? px[col] : 0.f;
                ya[j] = ok ? py[col] : 0.f;
            }
        }

        // MSE on raw pred over owned interior-row pixels (exact partition)
        if (r >= HALO && r < HALO + TY) {
#pragma unroll
            for (int c = 0; c < 4; ++c) {
                float d = xa[8 + c] - ya[8 + c];
                mse_local = fmaf(d, d, mse_local);
            }
        }
        // SSIM uses clipped pred (only positions 3..16 feed the conv)
#pragma unroll
        for (int j = 3; j < 17; ++j) xa[j] = fminf(fmaxf(xa[j], 0.f), 1.f);

        float a0[4] = {0,0,0,0}, a1[4] = {0,0,0,0}, a2[4] = {0,0,0,0};
        float a3[4] = {0,0,0,0}, a4[4] = {0,0,0,0};
#pragma unroll
        for (int k = 0; k < 11; ++k) {
            float w = gw[k];
#pragma unroll
            for (int c = 0; c < 4; ++c) {
                float xv = xa[3 + c + k], yv = ya[3 + c + k];
                float wx = w * xv, wy = w * yv;
                a0[c] += wx; a1[c] += wy;
                a2[c] = fmaf(wx, xv, a2[c]);
                a3[c] = fmaf(wy, yv, a3[c]);
                a4[c] = fmaf(wx, yv, a4[c]);
            }
        }
        *(float4*)&s_mxy[r][c0]     = make_float4(a0[0], a1[0], a0[1], a1[1]);
        *(float4*)&s_mxy[r][c0 + 2] = make_float4(a0[2], a1[2], a0[3], a1[3]);
        *(float4*)&s_sq [r][c0]     = make_float4(a2[0], a3[0], a2[1], a3[1]);
        *(float4*)&s_sq [r][c0 + 2] = make_float4(a2[2], a3[2], a2[3], a3[3]);
        *(float4*)&s_xy [r][c0]     = make_float4(a4[0], a4[1], a4[2], a4[3]);
    }
    __syncthreads();

    // ---- Phase 2: vertical 11-tap, 4-row run per thread (perfect balance) ----
    const int r4 = tid >> 6;   // wave id 0..3 -> output rows 4*r4 .. 4*r4+3
    const int c  = tid & 63;
    float ax[4]  = {0,0,0,0}, ay[4]  = {0,0,0,0};
    float axx[4] = {0,0,0,0}, ayy[4] = {0,0,0,0}, axy[4] = {0,0,0,0};
#pragma unroll
    for (int j = 0; j < 14; ++j) {
        float2 m2 = s_mxy[4 * r4 + j][c];
        float2 q2 = s_sq [4 * r4 + j][c];
        float  x1 = s_xy [4 * r4 + j][c];
#pragma unroll
        for (int k = 0; k < 4; ++k) {
            if (k <= j && j <= k + 10) {
                float w = gw[j - k];
                ax [k] = fmaf(w, m2.x, ax [k]);
                ay [k] = fmaf(w, m2.y, ay [k]);
                axx[k] = fmaf(w, q2.x, axx[k]);
                ayy[k] = fmaf(w, q2.y, ayy[k]);
                axy[k] = fmaf(w, x1,   axy[k]);
            }
        }
    }
    float ssim_local = 0.f;
    const float C1 = 1e-4f;   // (0.01*1)^2
    const float C2 = 9e-4f;   // (0.03*1)^2
#pragma unroll
    for (int k = 0; k < 4; ++k) {
        float mu_x2 = ax[k] * ax[k], mu_y2 = ay[k] * ay[k], mu_xy = ax[k] * ay[k];
        float sx2 = axx[k] - mu_x2, sy2 = ayy[k] - mu_y2, sxy = axy[k] - mu_xy;
        float num = (2.f * mu_xy + C1) * (2.f * sxy + C2);
        float den = (mu_x2 + mu_y2 + C1) * (sx2 + sy2 + C2);
        ssim_local = fmaf(num, __builtin_amdgcn_rcpf(den), ssim_local);
    }

    // ---- Per-wave reduction + spread f64 atomics (no extra barrier) ----
    float m = mse_local, s2 = ssim_local;
#pragma unroll
    for (int off = 32; off; off >>= 1) {
        m  += __shfl_down(m, off);
        s2 += __shfl_down(s2, off);
    }
    if ((tid & 63) == 0) {
        int flat = blockIdx.x + 8 * (blockIdx.y + 32 * blockIdx.z);
        int slot = (flat * 4 + r4) & (NSLOT - 1);
        atomicAdd(&ws[slot], (double)m);
        atomicAdd(&ws[NSLOT + slot], (double)s2);
    }
}

__global__ void hybrid_fin(const double* __restrict__ ws, float* __restrict__ out) {
    int t = threadIdx.x;  // 64 threads
    double m = ws[t] + ws[t + 64];
    double s = ws[NSLOT + t] + ws[NSLOT + t + 64];
#pragma unroll
    for (int off = 32; off; off >>= 1) {
        m += __shfl_down(m, off);
        s += __shfl_down(s, off);
    }
    if (t == 0) {
        const double N = (double)NIMG * H * W;
        double mse  = m / N;
        double ssim = s / N;
        out[0] = (float)(0.8 * mse + 0.2 * (1.0 - ssim));
    }
}

extern "C" void kernel_launch(void* const* d_in, const int* in_sizes, int n_in,
                              void* d_out, int out_size, void* d_ws, size_t ws_size,
                              hipStream_t stream) {
    const float* pred = (const float*)d_in[0];
    const float* targ = (const float*)d_in[1];
    double* ws = (double*)d_ws;
    float* out = (float*)d_out;

    hybrid_init<<<1, 256, 0, stream>>>(ws);
    dim3 grid(W / TX, H / TY, NIMG);
    hybrid_main<<<grid, dim3(256), 0, stream>>>(pred, targ, ws);
    hybrid_fin<<<1, 64, 0, stream>>>(ws, out);
}

// Round 4
// 144.366 us; speedup vs baseline: 1.8945x; 1.4736x over previous
//
#include <hip/hip_runtime.h>

// HybridLoss: 0.8*MSE + 0.2*(1-SSIM), SSIM via separable 11x11 Gaussian (sigma=1.5)
// Input: pred, target f32 (32,3,512,512). Output: scalar f32.
// Streaming strip: 64-wide x 128-tall per block, 16-row chunks through a
// 26-row circular LDS buffer of hconv results. Halo overhead 138/128 = 1.08x.

#define W 512
#define H 512
#define NIMG 96
#define TX 64
#define CHUNK 16
#define STRIP 128
#define NITER 8            // STRIP/CHUNK
#define BUF 26             // circular buffer rows (window = 26)
#define PAD2 66            // float2 row stride (conflict-free phase-1 writes)
#define NSLOT 128

__global__ void hybrid_init(double* __restrict__ ws) {
    int t = threadIdx.x;
    if (t < 2 * NSLOT) ws[t] = 0.0;
}

__global__ __launch_bounds__(256, 4) void hybrid_main(
    const float* __restrict__ pred, const float* __restrict__ targ,
    double* __restrict__ ws)
{
    __shared__ float2 s_mxy[BUF][PAD2];  // (mu_x, mu_y)  13728 B
    __shared__ float2 s_sq [BUF][PAD2];  // (xx, yy)      13728 B
    __shared__ float  s_xy [BUF][TX];    // xy             6656 B  -> 34.1 KB

    const int tid = threadIdx.x;
    const float* __restrict__ pp = pred + (size_t)blockIdx.z * (H * W);
    const float* __restrict__ tp = targ + (size_t)blockIdx.z * (H * W);
    const int xbase = blockIdx.x * TX;
    const int Y0 = blockIdx.y * STRIP;

    // Normalized 1D Gaussian (separable form of outer(g,g)/sum), f32 like ref
    float gw[11];
    {
        float s = 0.f;
#pragma unroll
        for (int k = 0; k < 11; ++k) {
            float d = (float)(k - 5);
            gw[k] = expf(-d * d / 4.5f);   // 2*sigma^2 = 4.5
            s += gw[k];
        }
        float inv = 1.f / s;
#pragma unroll
        for (int k = 0; k < 11; ++k) gw[k] *= inv;
    }

    const int hrow_i = tid >> 4;       // 0..15 : hconv row-in-chunk
    const int g      = tid & 15;       // 4-col group
    const int c0     = g * 4;
    const int A0     = xbase + c0 - 8; // aligned 20-px window [A0, A0+20)
    const bool inX   = (A0 >= 0) && (A0 + 20 <= W);

    const int wv = tid >> 6;           // wave 0..3 (vconv 4-row runs)
    const int cc = tid & 63;           // output column within tile

    float mse_local = 0.f, ssim_local = 0.f;

    // hconv one row (gy) into circular slot; MSE on raw pred if row is owned.
    auto hconv_row = [&](int gy, int slot, bool own) {
        float xa[20], ya[20];
        if (gy >= 0 && gy < H) {
            const float* __restrict__ px = pp + (size_t)gy * W;
            const float* __restrict__ py = tp + (size_t)gy * W;
            if (inX) {
                const float4* qx = (const float4*)(px + A0);
                const float4* qy = (const float4*)(py + A0);
#pragma unroll
                for (int v = 0; v < 5; ++v) {
                    float4 a = qx[v], b = qy[v];
                    xa[4*v+0]=a.x; xa[4*v+1]=a.y; xa[4*v+2]=a.z; xa[4*v+3]=a.w;
                    ya[4*v+0]=b.x; ya[4*v+1]=b.y; ya[4*v+2]=b.z; ya[4*v+3]=b.w;
                }
            } else {
#pragma unroll
                for (int j = 0; j < 20; ++j) {
                    int col = A0 + j;
                    bool ok = (col >= 0) && (col < W);
                    xa[j] = ok ? px[col] : 0.f;
                    ya[j] = ok ? py[col] : 0.f;
                }
            }
        } else {
#pragma unroll
            for (int j = 0; j < 20; ++j) { xa[j] = 0.f; ya[j] = 0.f; }
        }

        float a0[4]={0,0,0,0}, a1[4]={0,0,0,0}, a2[4]={0,0,0,0};
        float a3[4]={0,0,0,0}, a4[4]={0,0,0,0};
#pragma unroll
        for (int j = 0; j < 14; ++j) {        // window positions 3..16
            float xv = xa[3 + j], yv = ya[3 + j];
            if (j >= 5 && j <= 8 && own) {    // owned pixels, raw pred
                float d = xv - yv;
                mse_local = fmaf(d, d, mse_local);
            }
            float cx = fminf(fmaxf(xv, 0.f), 1.f);   // SSIM uses clipped pred
            float x2 = cx * cx, y2 = yv * yv, xy = cx * yv;
#pragma unroll
            for (int i = 0; i < 4; ++i) {
                int k = j - i;
                if (k >= 0 && k < 11) {
                    float w = gw[k];
                    a0[i] = fmaf(w, cx, a0[i]);
                    a1[i] = fmaf(w, yv, a1[i]);
                    a2[i] = fmaf(w, x2, a2[i]);
                    a3[i] = fmaf(w, y2, a3[i]);
                    a4[i] = fmaf(w, xy, a4[i]);
                }
            }
        }
        *(float4*)&s_mxy[slot][c0]     = make_float4(a0[0], a1[0], a0[1], a1[1]);
        *(float4*)&s_mxy[slot][c0 + 2] = make_float4(a0[2], a1[2], a0[3], a1[3]);
        *(float4*)&s_sq [slot][c0]     = make_float4(a2[0], a3[0], a2[1], a3[1]);
        *(float4*)&s_sq [slot][c0 + 2] = make_float4(a2[2], a3[2], a2[3], a3[3]);
        *(float4*)&s_xy [slot][c0]     = make_float4(a4[0], a4[1], a4[2], a4[3]);
    };

    // Prologue: ext rows 0..9 (gy = Y0-5 .. Y0+4) -> slots 0..9
    if (hrow_i < 10) {
        hconv_row(Y0 - 5 + hrow_i, hrow_i, hrow_i >= 5);
    }

    int hb = 10;   // slot of ext row 16k+10 (first hconv row of iter k)
    int vb = 0;    // slot of ext row 16k   (window base of iter k)
    const float C1 = 1e-4f, C2 = 9e-4f;

    for (int k = 0; k < NITER; ++k) {
        // ---- hconv-write: ext rows 16k+10 .. 16k+25 (1 task/thread) ----
        {
            int ext  = 16 * k + 10 + hrow_i;
            int slot = hb + hrow_i; if (slot >= BUF) slot -= BUF;
            hconv_row(Y0 - 5 + ext, slot, ext <= 132);
        }
        __syncthreads();

        // ---- vconv: output rows 16k + 4*wv .. +3 (1 task/thread) ----
        {
            int t0 = vb + 4 * wv; if (t0 >= BUF) t0 -= BUF;
            float ax[4]={0,0,0,0}, ay[4]={0,0,0,0};
            float axx[4]={0,0,0,0}, ayy[4]={0,0,0,0}, axy[4]={0,0,0,0};
#pragma unroll
            for (int j = 0; j < 14; ++j) {
                int s = t0 + j; if (s >= BUF) s -= BUF;
                float2 m2 = s_mxy[s][cc];
                float2 q2 = s_sq [s][cc];
                float  x1 = s_xy [s][cc];
#pragma unroll
                for (int i = 0; i < 4; ++i) {
                    int kk = j - i;
                    if (kk >= 0 && kk < 11) {
                        float w = gw[kk];
                        ax [i] = fmaf(w, m2.x, ax [i]);
                        ay [i] = fmaf(w, m2.y, ay [i]);
                        axx[i] = fmaf(w, q2.x, axx[i]);
                        ayy[i] = fmaf(w, q2.y, ayy[i]);
                        axy[i] = fmaf(w, x1,   axy[i]);
                    }
                }
            }
#pragma unroll
            for (int i = 0; i < 4; ++i) {
                float mu_x2 = ax[i]*ax[i], mu_y2 = ay[i]*ay[i], mu_xy = ax[i]*ay[i];
                float sx2 = axx[i]-mu_x2, sy2 = ayy[i]-mu_y2, sxy = axy[i]-mu_xy;
                float num = (2.f*mu_xy + C1) * (2.f*sxy + C2);
                float den = (mu_x2 + mu_y2 + C1) * (sx2 + sy2 + C2);
                ssim_local = fmaf(num, __builtin_amdgcn_rcpf(den), ssim_local);
            }
        }
        __syncthreads();

        hb += CHUNK; if (hb >= BUF) hb -= BUF;
        vb += CHUNK; if (vb >= BUF) vb -= BUF;
    }

    // ---- Per-wave reduction + spread f64 atomics ----
    float m = mse_local, s2 = ssim_local;
#pragma unroll
    for (int off = 32; off; off >>= 1) {
        m  += __shfl_down(m, off);
        s2 += __shfl_down(s2, off);
    }
    if ((tid & 63) == 0) {
        int flat = blockIdx.x + 8 * (blockIdx.y + 4 * blockIdx.z);
        int slot = (flat * 4 + wv) & (NSLOT - 1);
        atomicAdd(&ws[slot], (double)m);
        atomicAdd(&ws[NSLOT + slot], (double)s2);
    }
}

__global__ void hybrid_fin(const double* __restrict__ ws, float* __restrict__ out) {
    int t = threadIdx.x;  // 64 threads
    double m = ws[t] + ws[t + 64];
    double s = ws[NSLOT + t] + ws[NSLOT + t + 64];
#pragma unroll
    for (int off = 32; off; off >>= 1) {
        m += __shfl_down(m, off);
        s += __shfl_down(s, off);
    }
    if (t == 0) {
        const double N = (double)NIMG * H * W;
        double mse  = m / N;
        double ssim = s / N;
        out[0] = (float)(0.8 * mse + 0.2 * (1.0 - ssim));
    }
}

extern "C" void kernel_launch(void* const* d_in, const int* in_sizes, int n_in,
                              void* d_out, int out_size, void* d_ws, size_t ws_size,
                              hipStream_t stream) {
    const float* pred = (const float*)d_in[0];
    const float* targ = (const float*)d_in[1];
    double* ws = (double*)d_ws;
    float* out = (float*)d_out;

    hybrid_init<<<1, 256, 0, stream>>>(ws);
    dim3 grid(W / TX, H / STRIP, NIMG);
    hybrid_main<<<grid, dim3(256), 0, stream>>>(pred, targ, ws);
    hybrid_fin<<<1, 64, 0, stream>>>(ws, out);
}